// Round 2
// baseline (2094.922 us; speedup 1.0000x reference)
//
#include <hip/hip_runtime.h>

// Problem constants
namespace {
constexpr int Bc = 128, Lc = 36, Vc = 36, Dc = 512, KDc = 300, KVc = 112, Qc = 36, Hc = 512;
constexpr int ROWS = Bc * Lc * Vc;     // 165888 rows of (b,l,j)
constexpr int BLn  = Bc * Lc;          // 4608
constexpr int SLOT = Bc * Qc * Qc;     // 165888
constexpr float SCALE = 1.0f / 6.0f;   // 36^-0.5
}

__device__ __forceinline__ float wave_sum(float v) {
  #pragma unroll
  for (int off = 32; off > 0; off >>= 1) v += __shfl_xor(v, off, 64);
  return v;
}
__device__ __forceinline__ float wave_max(float v) {
  #pragma unroll
  for (int off = 32; off > 0; off >>= 1) v = fmaxf(v, __shfl_xor(v, off, 64));
  return v;
}
__device__ __forceinline__ float sigmoidf_(float x) { return 1.f / (1.f + __expf(-x)); }

// slots init: broadcast pano_a over batch
__global__ void init_slots_kernel(const float* __restrict__ pano, float* __restrict__ slots) {
  int idx = blockIdx.x * 256 + threadIdx.x;   // < 165888
  slots[idx] = pano[idx % (Qc * Qc)];
}

// csum[b][j][d] = sum_l ctx[b][l][j][d]
__global__ __launch_bounds__(256) void csum_kernel(const float* __restrict__ ctx, float* __restrict__ csum) {
  int tid = blockIdx.x * 256 + threadIdx.x;   // < B*V*D
  int b  = tid / (Vc * Dc);
  int jd = tid % (Vc * Dc);
  const float* p = ctx + (size_t)b * Lc * Vc * Dc + jd;
  float s = 0.f;
  #pragma unroll
  for (int l = 0; l < Lc; ++l) s += p[(size_t)l * (Vc * Dc)];
  csum[tid] = s;
}

// kd[bl][q] = sum_c det[bl][c] * Wk[q][512+c]
__global__ void kd_kernel(const float* __restrict__ det, const float* __restrict__ Wk,
                          float* __restrict__ kd) {
  __shared__ float ds[KDc];
  int bl = blockIdx.x; int t = threadIdx.x;
  for (int c = t; c < KDc; c += 64) ds[c] = det[(size_t)bl * KDc + c];
  __syncthreads();
  if (t < Qc) {
    const float* w = Wk + (size_t)t * 812 + 512;
    float acc = 0.f;
    #pragma unroll 4
    for (int c = 0; c < KDc; ++c) acc = fmaf(ds[c], w[c], acc);
    kd[(size_t)bl * Qc + t] = acc;
  }
}

// k[row][q] = sum_{d<512} ctx_flat[row][d]*Wk[q][d] + kd[row/36][q]
// tile: 256 rows x 36 cols, K-chunk 32; 648 blocks x 256 threads
__global__ __launch_bounds__(256) void k_gemm(const float* __restrict__ A, const float* __restrict__ Wk,
                       const float* __restrict__ kd, float* __restrict__ kout) {
  __shared__ __align__(16) float As[32 * 260];
  __shared__ __align__(16) float Bs[32 * 48];
  int t = threadIdx.x;
  int rb = blockIdx.x * 256;
  int tr = t & 63, tc = t >> 6;
  float acc[4][9];
  #pragma unroll
  for (int i = 0; i < 4; ++i)
    #pragma unroll
    for (int c = 0; c < 9; ++c) acc[i][c] = 0.f;

  for (int d0 = 0; d0 < 512; d0 += 32) {
    #pragma unroll
    for (int jj = 0; jj < 8; ++jj) {
      int idx = t + jj * 256;
      int kkb = (idx & 7) * 4, r = idx >> 3;
      const float4 v = *(const float4*)(A + (size_t)(rb + r) * 512 + d0 + kkb);
      As[(kkb + 0) * 260 + r] = v.x;
      As[(kkb + 1) * 260 + r] = v.y;
      As[(kkb + 2) * 260 + r] = v.z;
      As[(kkb + 3) * 260 + r] = v.w;
    }
    for (int idx = t; idx < 32 * 36; idx += 256) {
      int kk = idx / 36, c = idx % 36;
      Bs[kk * 48 + (c / 9) * 12 + (c % 9)] = Wk[(size_t)c * 812 + d0 + kk];
    }
    __syncthreads();
    #pragma unroll
    for (int kk = 0; kk < 32; ++kk) {
      const float4 a  = *(const float4*)&As[kk * 260 + tr * 4];
      const float* bp = &Bs[kk * 48 + tc * 12];
      const float4 b0 = *(const float4*)bp;
      const float4 b1 = *(const float4*)(bp + 4);
      const float  b8 = bp[8];
      const float av[4] = {a.x, a.y, a.z, a.w};
      const float bv[9] = {b0.x, b0.y, b0.z, b0.w, b1.x, b1.y, b1.z, b1.w, b8};
      #pragma unroll
      for (int i = 0; i < 4; ++i)
        #pragma unroll
        for (int c = 0; c < 9; ++c) acc[i][c] = fmaf(av[i], bv[c], acc[i][c]);
    }
    __syncthreads();
  }
  #pragma unroll
  for (int i = 0; i < 4; ++i) {
    int row = rb + tr * 4 + i;
    int bl = row / 36;
    #pragma unroll
    for (int c = 0; c < 9; ++c) {
      int q = tc * 9 + c;
      kout[(size_t)row * 36 + q] = acc[i][c] + kd[(size_t)bl * 36 + q];
    }
  }
}

// per batch: lnsum[e] = sum_i LN(slots[b,i,:])[e]; qsum[b,d] = sum_e lnsum[e]*Wq[d][e]
__global__ void lnqsum_kernel(const float* __restrict__ slots, const float* __restrict__ Wq,
                              const float* __restrict__ g, const float* __restrict__ bb,
                              float* __restrict__ qsum) {
  int b = blockIdx.x, lane = threadIdx.x;
  __shared__ float ls[Qc];
  float gv = 0.f, bv = 0.f;
  if (lane < Qc) { gv = g[lane]; bv = bb[lane]; }
  float lnsum = 0.f;
  for (int i = 0; i < Qc; ++i) {
    float x = (lane < Qc) ? slots[((size_t)b * Qc + i) * Qc + lane] : 0.f;
    float mu = wave_sum(x) * (1.f / 36.f);
    float d = x - mu;
    float var = wave_sum((lane < Qc) ? d * d : 0.f) * (1.f / 36.f);
    float ln = d * rsqrtf(var + 1e-5f) * gv + bv;
    if (lane < Qc) lnsum += ln;
  }
  if (lane < Qc) ls[lane] = lnsum;
  __syncthreads();
  if (lane < Qc) {
    float acc = 0.f;
    #pragma unroll
    for (int e = 0; e < Qc; ++e) acc = fmaf(ls[e], Wq[lane * Qc + e], acc);
    qsum[(size_t)b * Qc + lane] = acc;
  }
}

// dots over q (36) + softmax over j; one wave per (b,l); writes attn into d_out slab
__global__ void dots_kernel(const float* __restrict__ kmat, const float* __restrict__ qsum,
                            float* __restrict__ attn_out) {
  int bl = blockIdx.x;
  int b = bl / Lc;
  int lane = threadIdx.x;
  __shared__ float qs[Qc];
  if (lane < Qc) qs[lane] = qsum[(size_t)b * Qc + lane];
  __syncthreads();
  float dot = 0.f;
  if (lane < Vc) {
    const float* kp = kmat + ((size_t)bl * Vc + lane) * Qc;
    #pragma unroll
    for (int c = 0; c < 9; ++c) {
      float4 kv = *(const float4*)(kp + c * 4);
      dot += kv.x * qs[4 * c] + kv.y * qs[4 * c + 1] + kv.z * qs[4 * c + 2] + kv.w * qs[4 * c + 3];
    }
  }
  dot *= SCALE;
  float m = wave_max((lane < Vc) ? dot : -1e30f);
  float e = (lane < Vc) ? __expf(dot - m) : 0.f;
  float s = wave_sum(e);
  if (lane < Vc) attn_out[(size_t)bl * Vc + lane] = e / s;
}

// updates[b][i][d] = sum_j csum[b][j][d] * attn[b][i][j]; block=(b, d-half of 256)
__global__ __launch_bounds__(256) void updates_kernel(const float* __restrict__ csum, const float* __restrict__ attn,
                               float* __restrict__ upd) {
  int b = blockIdx.x >> 1;
  int d = (blockIdx.x & 1) * 256 + threadIdx.x;
  __shared__ __align__(16) float at[Qc * Vc];
  for (int idx = threadIdx.x; idx < Qc * Vc; idx += 256) at[idx] = attn[(size_t)b * Qc * Vc + idx];
  __syncthreads();
  float cj[36];
  #pragma unroll
  for (int j = 0; j < 36; ++j) cj[j] = csum[((size_t)b * Vc + j) * Dc + d];
  float acc[36];
  #pragma unroll
  for (int i = 0; i < 36; ++i) acc[i] = 0.f;
  #pragma unroll
  for (int i = 0; i < 36; ++i) {
    #pragma unroll
    for (int j4 = 0; j4 < 9; ++j4) {
      float4 av = *(const float4*)&at[i * 36 + j4 * 4];
      acc[i] += av.x * cj[4 * j4] + av.y * cj[4 * j4 + 1] + av.z * cj[4 * j4 + 2] + av.w * cj[4 * j4 + 3];
    }
  }
  #pragma unroll
  for (int i = 0; i < 36; ++i) upd[((size_t)b * 36 + i) * Dc + d] = acc[i];
}

// gx = x @ Wih^T, x = [upd(512) | knw(112)], split-K=13 (48 each), atomic accumulate
// tile 128 rows x 108 cols; grid 36*13; block 256 (thread = 2 rows x 27 cols)
__global__ __launch_bounds__(256) void gx_gemm(const float* __restrict__ upd, const float* __restrict__ knw,
                        const float* __restrict__ Wih, float* __restrict__ gx) {
  __shared__ __align__(16) float As[48 * 132];
  __shared__ __align__(16) float Bs[48 * 112];
  int t = threadIdx.x;
  int mt = blockIdx.x % 36, ks = blockIdx.x / 36;
  int rb = mt * 128, d0 = ks * 48;
  #pragma unroll
  for (int jj = 0; jj < 6; ++jj) {
    int idx = t + jj * 256;
    int kkb = (idx % 12) * 4, r = idx / 12;
    int d = d0 + kkb, row = rb + r;
    float4 v;
    if (d < 512) v = *(const float4*)(upd + (size_t)row * 512 + d);
    else         v = *(const float4*)(knw + (size_t)row * 112 + (d - 512));
    As[(kkb + 0) * 132 + r] = v.x;
    As[(kkb + 1) * 132 + r] = v.y;
    As[(kkb + 2) * 132 + r] = v.z;
    As[(kkb + 3) * 132 + r] = v.w;
  }
  for (int idx = t; idx < 108 * 48; idx += 256) {
    int kk = idx / 108, c = idx % 108;
    Bs[kk * 112 + (c / 27) * 28 + (c % 27)] = Wih[(size_t)c * 624 + d0 + kk];
  }
  __syncthreads();
  int tr = t & 63, tc = t >> 6;
  float acc[2][27];
  #pragma unroll
  for (int ri = 0; ri < 2; ++ri)
    #pragma unroll
    for (int c = 0; c < 27; ++c) acc[ri][c] = 0.f;
  #pragma unroll 4
  for (int kk = 0; kk < 48; ++kk) {
    const float2 a = *(const float2*)&As[kk * 132 + tr * 2];
    const float* bp = &Bs[kk * 112 + tc * 28];
    float bv[27];
    #pragma unroll
    for (int c4 = 0; c4 < 6; ++c4) {
      float4 b4 = *(const float4*)(bp + c4 * 4);
      bv[c4 * 4 + 0] = b4.x; bv[c4 * 4 + 1] = b4.y; bv[c4 * 4 + 2] = b4.z; bv[c4 * 4 + 3] = b4.w;
    }
    bv[24] = bp[24]; bv[25] = bp[25]; bv[26] = bp[26];
    #pragma unroll
    for (int c = 0; c < 27; ++c) {
      acc[0][c] = fmaf(a.x, bv[c], acc[0][c]);
      acc[1][c] = fmaf(a.y, bv[c], acc[1][c]);
    }
  }
  int row0 = rb + tr * 2;
  #pragma unroll
  for (int ri = 0; ri < 2; ++ri)
    #pragma unroll
    for (int c = 0; c < 27; ++c)
      atomicAdd(&gx[(size_t)(row0 + ri) * 108 + tc * 27 + c], acc[ri][c]);
}

// GRU gates + LN(ff) + snew init (= h' + b2); one wave per row
__global__ void gate_kernel(const float* __restrict__ slots, const float* __restrict__ gx,
                            const float* __restrict__ Whh, const float* __restrict__ bih,
                            const float* __restrict__ bhh, const float* __restrict__ lng,
                            const float* __restrict__ lnb, const float* __restrict__ b2,
                            float* __restrict__ ff, float* __restrict__ snew) {
  int row = blockIdx.x, lane = threadIdx.x;
  __shared__ float hps[Qc];
  float hp = 0.f;
  if (lane < Qc) { hp = slots[(size_t)row * Qc + lane]; hps[lane] = hp; }
  __syncthreads();
  float hprime = 0.f;
  if (lane < Qc) {
    float hr = bhh[lane], hz = bhh[36 + lane], hn = bhh[72 + lane];
    #pragma unroll 4
    for (int e = 0; e < Qc; ++e) {
      float h = hps[e];
      hr = fmaf(h, Whh[lane * 36 + e], hr);
      hz = fmaf(h, Whh[(36 + lane) * 36 + e], hz);
      hn = fmaf(h, Whh[(72 + lane) * 36 + e], hn);
    }
    float xr = gx[(size_t)row * 108 + lane]      + bih[lane];
    float xz = gx[(size_t)row * 108 + 36 + lane] + bih[36 + lane];
    float xn = gx[(size_t)row * 108 + 72 + lane] + bih[72 + lane];
    float r = sigmoidf_(xr + hr);
    float z = sigmoidf_(xz + hz);
    float n = tanhf(xn + r * hn);
    hprime = (1.f - z) * n + z * hp;
  }
  float mu = wave_sum((lane < Qc) ? hprime : 0.f) * (1.f / 36.f);
  float dd = hprime - mu;
  float var = wave_sum((lane < Qc) ? dd * dd : 0.f) * (1.f / 36.f);
  float rstd = rsqrtf(var + 1e-5f);
  if (lane < Qc) {
    ff[(size_t)row * Qc + lane]   = dd * rstd * lng[lane] + lnb[lane];
    snew[(size_t)row * Qc + lane] = hprime + b2[lane];
  }
}

// mid = relu(ff @ W1^T + b1): M=4608,N=512,K=36; tile 64x128; grid 72*4
__global__ __launch_bounds__(256) void mlp1_kernel(const float* __restrict__ ff, const float* __restrict__ W1,
                         const float* __restrict__ b1, float* __restrict__ mid) {
  __shared__ __align__(16) float As[36 * 68];
  __shared__ __align__(16) float Bs[36 * 132];
  int t = threadIdx.x;
  int mt = blockIdx.x % 72, nt = blockIdx.x / 72;
  int rb = mt * 64, cb = nt * 128;
  for (int idx = t; idx < 64 * 36; idx += 256) {
    int r = idx / 36, e = idx % 36;
    As[e * 68 + r] = ff[(size_t)(rb + r) * 36 + e];
  }
  for (int idx = t; idx < 128 * 36; idx += 256) {
    int c = idx / 36, e = idx % 36;
    Bs[e * 132 + c] = W1[(size_t)(cb + c) * 36 + e];
  }
  __syncthreads();
  int tr = t & 31, tc = t >> 5;
  float acc[2][16];
  #pragma unroll
  for (int ri = 0; ri < 2; ++ri)
    #pragma unroll
    for (int c = 0; c < 16; ++c) acc[ri][c] = 0.f;
  #pragma unroll 4
  for (int e = 0; e < 36; ++e) {
    const float2 a = *(const float2*)&As[e * 68 + tr * 2];
    const float* bp = &Bs[e * 132 + tc * 16];
    float bv[16];
    #pragma unroll
    for (int c4 = 0; c4 < 4; ++c4) {
      float4 b4 = *(const float4*)(bp + c4 * 4);
      bv[c4 * 4 + 0] = b4.x; bv[c4 * 4 + 1] = b4.y; bv[c4 * 4 + 2] = b4.z; bv[c4 * 4 + 3] = b4.w;
    }
    #pragma unroll
    for (int c = 0; c < 16; ++c) {
      acc[0][c] = fmaf(a.x, bv[c], acc[0][c]);
      acc[1][c] = fmaf(a.y, bv[c], acc[1][c]);
    }
  }
  #pragma unroll
  for (int ri = 0; ri < 2; ++ri) {
    int row = rb + tr * 2 + ri;
    #pragma unroll
    for (int c4 = 0; c4 < 4; ++c4) {
      int c0 = cb + tc * 16 + c4 * 4;
      float4 o;
      o.x = fmaxf(acc[ri][c4 * 4 + 0] + b1[c0 + 0], 0.f);
      o.y = fmaxf(acc[ri][c4 * 4 + 1] + b1[c0 + 1], 0.f);
      o.z = fmaxf(acc[ri][c4 * 4 + 2] + b1[c0 + 2], 0.f);
      o.w = fmaxf(acc[ri][c4 * 4 + 3] + b1[c0 + 3], 0.f);
      *(float4*)&mid[(size_t)row * 512 + c0] = o;
    }
  }
}

// snew += mid @ W2^T: M=4608,N=36,K=512 split 4; tile 64 rows; grid 72*4
__global__ __launch_bounds__(256) void mlp2_kernel(const float* __restrict__ mid, const float* __restrict__ W2,
                         float* __restrict__ snew) {
  __shared__ __align__(16) float As[32 * 68];
  __shared__ __align__(16) float Bs[32 * 48];
  int t = threadIdx.x;
  int mt = blockIdx.x % 72, ks = blockIdx.x / 72;
  int rb = mt * 64;
  int tr = t & 63, tc = t >> 6;
  float acc[9];
  #pragma unroll
  for (int c = 0; c < 9; ++c) acc[c] = 0.f;
  for (int d0 = ks * 128; d0 < ks * 128 + 128; d0 += 32) {
    #pragma unroll
    for (int jj = 0; jj < 2; ++jj) {
      int idx = t + jj * 256;
      int kkb = (idx & 7) * 4, r = idx >> 3;
      const float4 v = *(const float4*)(mid + (size_t)(rb + r) * 512 + d0 + kkb);
      As[(kkb + 0) * 68 + r] = v.x;
      As[(kkb + 1) * 68 + r] = v.y;
      As[(kkb + 2) * 68 + r] = v.z;
      As[(kkb + 3) * 68 + r] = v.w;
    }
    for (int idx = t; idx < 36 * 32; idx += 256) {
      int kk = idx / 36, c = idx % 36;
      Bs[kk * 48 + (c / 9) * 12 + (c % 9)] = W2[(size_t)c * 512 + d0 + kk];
    }
    __syncthreads();
    #pragma unroll
    for (int kk = 0; kk < 32; ++kk) {
      const float a = As[kk * 68 + tr];
      const float* bp = &Bs[kk * 48 + tc * 12];
      const float4 b0 = *(const float4*)bp;
      const float4 b1 = *(const float4*)(bp + 4);
      const float  b8 = bp[8];
      const float bv[9] = {b0.x, b0.y, b0.z, b0.w, b1.x, b1.y, b1.z, b1.w, b8};
      #pragma unroll
      for (int c = 0; c < 9; ++c) acc[c] = fmaf(a, bv[c], acc[c]);
    }
    __syncthreads();
  }
  int row = rb + tr;
  #pragma unroll
  for (int c = 0; c < 9; ++c)
    atomicAdd(&snew[(size_t)row * 36 + tc * 9 + c], acc[c]);
}

__global__ void copy_kernel(const float* __restrict__ src, float* __restrict__ dst) {
  int idx = blockIdx.x * 256 + threadIdx.x;
  dst[idx] = src[idx];
}

extern "C" void kernel_launch(void* const* d_in, const int* in_sizes, int n_in,
                              void* d_out, int out_size, void* d_ws, size_t ws_size,
                              hipStream_t stream) {
  const float* ctx  = (const float*)d_in[1];
  const float* det  = (const float*)d_in[3];
  const float* knw  = (const float*)d_in[4];
  const float* pano = (const float*)d_in[5];
  const float* Wq   = (const float*)d_in[6];
  const float* Wk   = (const float*)d_in[7];
  const float* Wih  = (const float*)d_in[8];
  const float* Whh  = (const float*)d_in[9];
  const float* bih  = (const float*)d_in[10];
  const float* bhh  = (const float*)d_in[11];
  const float* lsg  = (const float*)d_in[12];
  const float* lsb  = (const float*)d_in[13];
  const float* lfg  = (const float*)d_in[14];
  const float* lfb  = (const float*)d_in[15];
  const float* W1   = (const float*)d_in[16];
  const float* b1   = (const float*)d_in[17];
  const float* W2   = (const float*)d_in[18];
  const float* b2   = (const float*)d_in[19];
  float* out = (float*)d_out;

  float* w = (float*)d_ws;
  float* kmat   = w; w += (size_t)ROWS * 36;      // 5971968
  float* csum   = w; w += (size_t)Bc * Vc * Dc;   // 2359296
  float* kd     = w; w += (size_t)BLn * Qc;       // 165888
  float* slotsA = w; w += SLOT;                   // 165888
  float* slotsB = w; w += SLOT;                   // 165888
  float* qsum   = w; w += Bc * Qc;                // 4608
  float* gx     = w; w += (size_t)BLn * 108;      // 497664
  float* upd    = w; w += (size_t)BLn * Dc;       // 2359296 (overlaid with mid)
  float* mid    = upd;                            // safe: upd consumed before mid written
  float* ffb    = w; w += SLOT;                   // 165888

  float* cur = slotsA;
  float* nxt = slotsB;

  init_slots_kernel<<<648, 256, 0, stream>>>(pano, cur);
  csum_kernel<<<(Bc * Vc * Dc) / 256, 256, 0, stream>>>(ctx, csum);
  kd_kernel<<<BLn, 64, 0, stream>>>(det, Wk, kd);
  k_gemm<<<ROWS / 256, 256, 0, stream>>>(ctx, Wk, kd, kmat);

  for (int it = 0; it < 3; ++it) {
    float* attn = out + SLOT + (size_t)it * SLOT;
    lnqsum_kernel<<<Bc, 64, 0, stream>>>(cur, Wq, lsg, lsb, qsum);
    dots_kernel<<<BLn, 64, 0, stream>>>(kmat, qsum, attn);
    updates_kernel<<<Bc * 2, 256, 0, stream>>>(csum, attn, upd);
    hipMemsetAsync(gx, 0, (size_t)BLn * 108 * sizeof(float), stream);
    gx_gemm<<<36 * 13, 256, 0, stream>>>(upd, knw, Wih, gx);
    gate_kernel<<<BLn, 64, 0, stream>>>(cur, gx, Whh, bih, bhh, lfg, lfb, b2, ffb, nxt);
    mlp1_kernel<<<72 * 4, 256, 0, stream>>>(ffb, W1, b1, mid);
    mlp2_kernel<<<72 * 4, 256, 0, stream>>>(mid, W2, nxt);
    float* tmp = cur; cur = nxt; nxt = tmp;
  }
  copy_kernel<<<SLOT / 256, 256, 0, stream>>>(cur, out);
}

// Round 3
// 1166.516 us; speedup vs baseline: 1.7959x; 1.7959x over previous
//
#include <hip/hip_runtime.h>

// Problem constants
namespace {
constexpr int Bc = 128, Lc = 36, Vc = 36, Dc = 512, KDc = 300, KVc = 112, Qc = 36, Hc = 512;
constexpr int ROWS = Bc * Lc * Vc;     // 165888 rows of (b,l,j)
constexpr int BLn  = Bc * Lc;          // 4608
constexpr int SLOT = Bc * Qc * Qc;     // 165888
constexpr float SCALE = 1.0f / 6.0f;   // 36^-0.5
}

__device__ __forceinline__ float wave_sum(float v) {
  #pragma unroll
  for (int off = 32; off > 0; off >>= 1) v += __shfl_xor(v, off, 64);
  return v;
}
__device__ __forceinline__ float wave_max(float v) {
  #pragma unroll
  for (int off = 32; off > 0; off >>= 1) v = fmaxf(v, __shfl_xor(v, off, 64));
  return v;
}
__device__ __forceinline__ float sigmoidf_(float x) { return 1.f / (1.f + __expf(-x)); }

// slots init: broadcast pano_a over batch
__global__ void init_slots_kernel(const float* __restrict__ pano, float* __restrict__ slots) {
  int idx = blockIdx.x * 256 + threadIdx.x;   // < 165888
  slots[idx] = pano[idx % (Qc * Qc)];
}

// csum[b][j][d] = sum_l ctx[b][l][j][d]
__global__ __launch_bounds__(256) void csum_kernel(const float* __restrict__ ctx, float* __restrict__ csum) {
  int tid = blockIdx.x * 256 + threadIdx.x;   // < B*V*D
  int b  = tid / (Vc * Dc);
  int jd = tid % (Vc * Dc);
  const float* p = ctx + (size_t)b * Lc * Vc * Dc + jd;
  float s = 0.f;
  #pragma unroll
  for (int l = 0; l < Lc; ++l) s += p[(size_t)l * (Vc * Dc)];
  csum[tid] = s;
}

// kd[bl][q] = sum_c det[bl][c] * Wk[q][512+c]
__global__ void kd_kernel(const float* __restrict__ det, const float* __restrict__ Wk,
                          float* __restrict__ kd) {
  __shared__ float ds[KDc];
  int bl = blockIdx.x; int t = threadIdx.x;
  for (int c = t; c < KDc; c += 64) ds[c] = det[(size_t)bl * KDc + c];
  __syncthreads();
  if (t < Qc) {
    const float* w = Wk + (size_t)t * 812 + 512;
    float acc = 0.f;
    #pragma unroll 4
    for (int c = 0; c < KDc; ++c) acc = fmaf(ds[c], w[c], acc);
    kd[(size_t)bl * Qc + t] = acc;
  }
}

// k[row][q] = sum_{d<512} ctx_flat[row][d]*Wk[q][d] + kd[row/36][q]
// tile: 256 rows x 36 cols, K-chunk 32; 648 blocks x 256 threads
__global__ __launch_bounds__(256) void k_gemm(const float* __restrict__ A, const float* __restrict__ Wk,
                       const float* __restrict__ kd, float* __restrict__ kout) {
  __shared__ __align__(16) float As[32 * 260];
  __shared__ __align__(16) float Bs[32 * 48];
  int t = threadIdx.x;
  int rb = blockIdx.x * 256;
  int tr = t & 63, tc = t >> 6;
  float acc[4][9];
  #pragma unroll
  for (int i = 0; i < 4; ++i)
    #pragma unroll
    for (int c = 0; c < 9; ++c) acc[i][c] = 0.f;

  for (int d0 = 0; d0 < 512; d0 += 32) {
    #pragma unroll
    for (int jj = 0; jj < 8; ++jj) {
      int idx = t + jj * 256;
      int kkb = (idx & 7) * 4, r = idx >> 3;
      const float4 v = *(const float4*)(A + (size_t)(rb + r) * 512 + d0 + kkb);
      As[(kkb + 0) * 260 + r] = v.x;
      As[(kkb + 1) * 260 + r] = v.y;
      As[(kkb + 2) * 260 + r] = v.z;
      As[(kkb + 3) * 260 + r] = v.w;
    }
    for (int idx = t; idx < 32 * 36; idx += 256) {
      int kk = idx / 36, c = idx % 36;
      Bs[kk * 48 + (c / 9) * 12 + (c % 9)] = Wk[(size_t)c * 812 + d0 + kk];
    }
    __syncthreads();
    #pragma unroll
    for (int kk = 0; kk < 32; ++kk) {
      const float4 a  = *(const float4*)&As[kk * 260 + tr * 4];
      const float* bp = &Bs[kk * 48 + tc * 12];
      const float4 b0 = *(const float4*)bp;
      const float4 b1 = *(const float4*)(bp + 4);
      const float  b8 = bp[8];
      const float av[4] = {a.x, a.y, a.z, a.w};
      const float bv[9] = {b0.x, b0.y, b0.z, b0.w, b1.x, b1.y, b1.z, b1.w, b8};
      #pragma unroll
      for (int i = 0; i < 4; ++i)
        #pragma unroll
        for (int c = 0; c < 9; ++c) acc[i][c] = fmaf(av[i], bv[c], acc[i][c]);
    }
    __syncthreads();
  }
  #pragma unroll
  for (int i = 0; i < 4; ++i) {
    int row = rb + tr * 4 + i;
    int bl = row / 36;
    #pragma unroll
    for (int c = 0; c < 9; ++c) {
      int q = tc * 9 + c;
      kout[(size_t)row * 36 + q] = acc[i][c] + kd[(size_t)bl * 36 + q];
    }
  }
}

// generic small GEMM vs Wih: outp[row][c] = sum_k A[row*lda+k] * Wih[c*624 + k0 + k]
// c < 108; 64-row tiles (grid 72); K multiple of 16; no atomics
__global__ __launch_bounds__(256) void prew_gemm(const float* __restrict__ A, int lda, int K, int k0,
                                                 const float* __restrict__ Wih, float* __restrict__ outp) {
  __shared__ __align__(16) float As[16 * 68];   // [k][row]
  __shared__ __align__(16) float Bs[16 * 112];  // [k][col grouped 28]
  int t = threadIdx.x;
  int rb = blockIdx.x * 64;
  int tr = t & 63, tc = t >> 6;      // tc in 0..3, 27 cols each
  float acc[27];
  #pragma unroll
  for (int c = 0; c < 27; ++c) acc[c] = 0.f;

  for (int kk0 = 0; kk0 < K; kk0 += 16) {
    {
      int r = t >> 2, kq = (t & 3) * 4;
      const float4 v = *(const float4*)(A + (size_t)(rb + r) * lda + kk0 + kq);
      As[(kq + 0) * 68 + r] = v.x;
      As[(kq + 1) * 68 + r] = v.y;
      As[(kq + 2) * 68 + r] = v.z;
      As[(kq + 3) * 68 + r] = v.w;
    }
    for (int idx = t; idx < 16 * 108; idx += 256) {
      int k = idx / 108, c = idx % 108;
      Bs[k * 112 + (c / 27) * 28 + (c % 27)] = Wih[(size_t)c * 624 + k0 + kk0 + k];
    }
    __syncthreads();
    #pragma unroll
    for (int k = 0; k < 16; ++k) {
      const float a = As[k * 68 + tr];
      const float* bp = &Bs[k * 112 + tc * 28];
      float bv[27];
      #pragma unroll
      for (int c4 = 0; c4 < 6; ++c4) {
        float4 b4 = *(const float4*)(bp + c4 * 4);
        bv[c4 * 4 + 0] = b4.x; bv[c4 * 4 + 1] = b4.y; bv[c4 * 4 + 2] = b4.z; bv[c4 * 4 + 3] = b4.w;
      }
      bv[24] = bp[24]; bv[25] = bp[25]; bv[26] = bp[26];
      #pragma unroll
      for (int c = 0; c < 27; ++c) acc[c] = fmaf(a, bv[c], acc[c]);
    }
    __syncthreads();
  }
  int row = rb + tr;
  #pragma unroll
  for (int c = 0; c < 27; ++c)
    outp[(size_t)row * 108 + tc * 27 + c] = acc[c];
}

// per batch: lnsum[e] = sum_i LN(slots[b,i,:])[e]; qsum[b,d] = sum_e lnsum[e]*Wq[d][e]
__global__ void lnqsum_kernel(const float* __restrict__ slots, const float* __restrict__ Wq,
                              const float* __restrict__ g, const float* __restrict__ bb,
                              float* __restrict__ qsum) {
  int b = blockIdx.x, lane = threadIdx.x;
  __shared__ float ls[Qc];
  float gv = 0.f, bv = 0.f;
  if (lane < Qc) { gv = g[lane]; bv = bb[lane]; }
  float lnsum = 0.f;
  for (int i = 0; i < Qc; ++i) {
    float x = (lane < Qc) ? slots[((size_t)b * Qc + i) * Qc + lane] : 0.f;
    float mu = wave_sum(x) * (1.f / 36.f);
    float d = x - mu;
    float var = wave_sum((lane < Qc) ? d * d : 0.f) * (1.f / 36.f);
    float ln = d * rsqrtf(var + 1e-5f) * gv + bv;
    if (lane < Qc) lnsum += ln;
  }
  if (lane < Qc) ls[lane] = lnsum;
  __syncthreads();
  if (lane < Qc) {
    float acc = 0.f;
    #pragma unroll
    for (int e = 0; e < Qc; ++e) acc = fmaf(ls[e], Wq[lane * Qc + e], acc);
    qsum[(size_t)b * Qc + lane] = acc;
  }
}

// dots over q (36) + softmax over j; one wave per (b,l); writes attn into d_out slab
__global__ void dots_kernel(const float* __restrict__ kmat, const float* __restrict__ qsum,
                            float* __restrict__ attn_out) {
  int bl = blockIdx.x;
  int b = bl / Lc;
  int lane = threadIdx.x;
  __shared__ float qs[Qc];
  if (lane < Qc) qs[lane] = qsum[(size_t)b * Qc + lane];
  __syncthreads();
  float dot = 0.f;
  if (lane < Vc) {
    const float* kp = kmat + ((size_t)bl * Vc + lane) * Qc;
    #pragma unroll
    for (int c = 0; c < 9; ++c) {
      float4 kv = *(const float4*)(kp + c * 4);
      dot += kv.x * qs[4 * c] + kv.y * qs[4 * c + 1] + kv.z * qs[4 * c + 2] + kv.w * qs[4 * c + 3];
    }
  }
  dot *= SCALE;
  float m = wave_max((lane < Vc) ? dot : -1e30f);
  float e = (lane < Vc) ? __expf(dot - m) : 0.f;
  float s = wave_sum(e);
  if (lane < Vc) attn_out[(size_t)bl * Vc + lane] = e / s;
}

// gx[b][i][c] = sum_j attn[b][i][j] * cw[b][j][c] + gknw[b][i][c]; grid Bc, 128 threads
__global__ __launch_bounds__(128) void gxmix_kernel(const float* __restrict__ attn, const float* __restrict__ cw,
                             const float* __restrict__ gknw, float* __restrict__ gx) {
  int b = blockIdx.x;
  int c = threadIdx.x;
  __shared__ float at[Qc * Vc];
  for (int idx = threadIdx.x; idx < Qc * Vc; idx += 128) at[idx] = attn[(size_t)b * Qc * Vc + idx];
  __syncthreads();
  if (c >= 108) return;
  float cwv[36];
  #pragma unroll
  for (int j = 0; j < 36; ++j) cwv[j] = cw[((size_t)b * 36 + j) * 108 + c];
  #pragma unroll 2
  for (int i = 0; i < 36; ++i) {
    float acc = gknw[((size_t)b * 36 + i) * 108 + c];
    #pragma unroll
    for (int j = 0; j < 36; ++j) acc = fmaf(at[i * 36 + j], cwv[j], acc);
    gx[((size_t)b * 36 + i) * 108 + c] = acc;
  }
}

// GRU gates + LN(ff) + snew init (= h' + b2); one wave per row
__global__ void gate_kernel(const float* __restrict__ slots, const float* __restrict__ gx,
                            const float* __restrict__ Whh, const float* __restrict__ bih,
                            const float* __restrict__ bhh, const float* __restrict__ lng,
                            const float* __restrict__ lnb, const float* __restrict__ b2,
                            float* __restrict__ ff, float* __restrict__ snew) {
  int row = blockIdx.x, lane = threadIdx.x;
  __shared__ float hps[Qc];
  float hp = 0.f;
  if (lane < Qc) { hp = slots[(size_t)row * Qc + lane]; hps[lane] = hp; }
  __syncthreads();
  float hprime = 0.f;
  if (lane < Qc) {
    float hr = bhh[lane], hz = bhh[36 + lane], hn = bhh[72 + lane];
    #pragma unroll 4
    for (int e = 0; e < Qc; ++e) {
      float h = hps[e];
      hr = fmaf(h, Whh[lane * 36 + e], hr);
      hz = fmaf(h, Whh[(36 + lane) * 36 + e], hz);
      hn = fmaf(h, Whh[(72 + lane) * 36 + e], hn);
    }
    float xr = gx[(size_t)row * 108 + lane]      + bih[lane];
    float xz = gx[(size_t)row * 108 + 36 + lane] + bih[36 + lane];
    float xn = gx[(size_t)row * 108 + 72 + lane] + bih[72 + lane];
    float r = sigmoidf_(xr + hr);
    float z = sigmoidf_(xz + hz);
    float n = tanhf(xn + r * hn);
    hprime = (1.f - z) * n + z * hp;
  }
  float mu = wave_sum((lane < Qc) ? hprime : 0.f) * (1.f / 36.f);
  float dd = hprime - mu;
  float var = wave_sum((lane < Qc) ? dd * dd : 0.f) * (1.f / 36.f);
  float rstd = rsqrtf(var + 1e-5f);
  if (lane < Qc) {
    ff[(size_t)row * Qc + lane]   = dd * rstd * lng[lane] + lnb[lane];
    snew[(size_t)row * Qc + lane] = hprime + b2[lane];
  }
}

// mid = relu(ff @ W1^T + b1): M=4608,N=512,K=36; tile 64x128; grid 72*4
__global__ __launch_bounds__(256) void mlp1_kernel(const float* __restrict__ ff, const float* __restrict__ W1,
                         const float* __restrict__ b1, float* __restrict__ mid) {
  __shared__ __align__(16) float As[36 * 68];
  __shared__ __align__(16) float Bs[36 * 132];
  int t = threadIdx.x;
  int mt = blockIdx.x % 72, nt = blockIdx.x / 72;
  int rb = mt * 64, cb = nt * 128;
  for (int idx = t; idx < 64 * 36; idx += 256) {
    int r = idx / 36, e = idx % 36;
    As[e * 68 + r] = ff[(size_t)(rb + r) * 36 + e];
  }
  for (int idx = t; idx < 128 * 36; idx += 256) {
    int c = idx / 36, e = idx % 36;
    Bs[e * 132 + c] = W1[(size_t)(cb + c) * 36 + e];
  }
  __syncthreads();
  int tr = t & 31, tc = t >> 5;
  float acc[2][16];
  #pragma unroll
  for (int ri = 0; ri < 2; ++ri)
    #pragma unroll
    for (int c = 0; c < 16; ++c) acc[ri][c] = 0.f;
  #pragma unroll 4
  for (int e = 0; e < 36; ++e) {
    const float2 a = *(const float2*)&As[e * 68 + tr * 2];
    const float* bp = &Bs[e * 132 + tc * 16];
    float bv[16];
    #pragma unroll
    for (int c4 = 0; c4 < 4; ++c4) {
      float4 b4 = *(const float4*)(bp + c4 * 4);
      bv[c4 * 4 + 0] = b4.x; bv[c4 * 4 + 1] = b4.y; bv[c4 * 4 + 2] = b4.z; bv[c4 * 4 + 3] = b4.w;
    }
    #pragma unroll
    for (int c = 0; c < 16; ++c) {
      acc[0][c] = fmaf(a.x, bv[c], acc[0][c]);
      acc[1][c] = fmaf(a.y, bv[c], acc[1][c]);
    }
  }
  #pragma unroll
  for (int ri = 0; ri < 2; ++ri) {
    int row = rb + tr * 2 + ri;
    #pragma unroll
    for (int c4 = 0; c4 < 4; ++c4) {
      int c0 = cb + tc * 16 + c4 * 4;
      float4 o;
      o.x = fmaxf(acc[ri][c4 * 4 + 0] + b1[c0 + 0], 0.f);
      o.y = fmaxf(acc[ri][c4 * 4 + 1] + b1[c0 + 1], 0.f);
      o.z = fmaxf(acc[ri][c4 * 4 + 2] + b1[c0 + 2], 0.f);
      o.w = fmaxf(acc[ri][c4 * 4 + 3] + b1[c0 + 3], 0.f);
      *(float4*)&mid[(size_t)row * 512 + c0] = o;
    }
  }
}

// snew += mid @ W2^T: M=4608,N=36,K=512 full; tile 64 rows; grid 72; NO atomics
__global__ __launch_bounds__(256) void mlp2_kernel(const float* __restrict__ mid, const float* __restrict__ W2,
                         float* __restrict__ snew) {
  __shared__ __align__(16) float As[32 * 68];
  __shared__ __align__(16) float Bs[32 * 48];
  int t = threadIdx.x;
  int rb = blockIdx.x * 64;
  int tr = t & 63, tc = t >> 6;
  float acc[9];
  #pragma unroll
  for (int c = 0; c < 9; ++c) acc[c] = 0.f;
  for (int d0 = 0; d0 < 512; d0 += 32) {
    #pragma unroll
    for (int jj = 0; jj < 2; ++jj) {
      int idx = t + jj * 256;
      int kkb = (idx & 7) * 4, r = idx >> 3;
      const float4 v = *(const float4*)(mid + (size_t)(rb + r) * 512 + d0 + kkb);
      As[(kkb + 0) * 68 + r] = v.x;
      As[(kkb + 1) * 68 + r] = v.y;
      As[(kkb + 2) * 68 + r] = v.z;
      As[(kkb + 3) * 68 + r] = v.w;
    }
    for (int idx = t; idx < 36 * 32; idx += 256) {
      int kk = idx / 36, c = idx % 36;
      Bs[kk * 48 + (c / 9) * 12 + (c % 9)] = W2[(size_t)c * 512 + d0 + kk];
    }
    __syncthreads();
    #pragma unroll
    for (int kk = 0; kk < 32; ++kk) {
      const float a = As[kk * 68 + tr];
      const float* bp = &Bs[kk * 48 + tc * 12];
      const float4 b0 = *(const float4*)bp;
      const float4 b1 = *(const float4*)(bp + 4);
      const float  b8 = bp[8];
      const float bv[9] = {b0.x, b0.y, b0.z, b0.w, b1.x, b1.y, b1.z, b1.w, b8};
      #pragma unroll
      for (int c = 0; c < 9; ++c) acc[c] = fmaf(a, bv[c], acc[c]);
    }
    __syncthreads();
  }
  int row = rb + tr;
  #pragma unroll
  for (int c = 0; c < 9; ++c) {
    size_t o = (size_t)row * 36 + tc * 9 + c;
    snew[o] = snew[o] + acc[c];
  }
}

__global__ void copy_kernel(const float* __restrict__ src, float* __restrict__ dst) {
  int idx = blockIdx.x * 256 + threadIdx.x;
  dst[idx] = src[idx];
}

extern "C" void kernel_launch(void* const* d_in, const int* in_sizes, int n_in,
                              void* d_out, int out_size, void* d_ws, size_t ws_size,
                              hipStream_t stream) {
  const float* ctx  = (const float*)d_in[1];
  const float* det  = (const float*)d_in[3];
  const float* knw  = (const float*)d_in[4];
  const float* pano = (const float*)d_in[5];
  const float* Wq   = (const float*)d_in[6];
  const float* Wk   = (const float*)d_in[7];
  const float* Wih  = (const float*)d_in[8];
  const float* Whh  = (const float*)d_in[9];
  const float* bih  = (const float*)d_in[10];
  const float* bhh  = (const float*)d_in[11];
  const float* lsg  = (const float*)d_in[12];
  const float* lsb  = (const float*)d_in[13];
  const float* lfg  = (const float*)d_in[14];
  const float* lfb  = (const float*)d_in[15];
  const float* W1   = (const float*)d_in[16];
  const float* b1   = (const float*)d_in[17];
  const float* W2   = (const float*)d_in[18];
  const float* b2   = (const float*)d_in[19];
  float* out = (float*)d_out;

  float* w = (float*)d_ws;
  float* kmat   = w; w += (size_t)ROWS * 36;      // 5971968 (24 MB)
  float* csum   = w; w += (size_t)Bc * Vc * Dc;   // 2359296 (9.4 MB)
  float* mid    = csum;                           // overlay: csum dead after cw_gemm
  float* kd     = w; w += (size_t)BLn * Qc;       // 165888
  float* slotsA = w; w += SLOT;                   // 165888
  float* slotsB = w; w += SLOT;                   // 165888
  float* qsum   = w; w += Bc * Qc;                // 4608
  float* cw     = w; w += (size_t)BLn * 108;      // 497664 (2 MB)
  float* gknw   = w; w += (size_t)BLn * 108;      // 497664 (2 MB)
  float* gx     = w; w += (size_t)BLn * 108;      // 497664 (2 MB)
  float* ffb    = w; w += SLOT;                   // 165888

  float* cur = slotsA;
  float* nxt = slotsB;

  init_slots_kernel<<<648, 256, 0, stream>>>(pano, cur);
  csum_kernel<<<(Bc * Vc * Dc) / 256, 256, 0, stream>>>(ctx, csum);
  kd_kernel<<<BLn, 64, 0, stream>>>(det, Wk, kd);
  k_gemm<<<ROWS / 256, 256, 0, stream>>>(ctx, Wk, kd, kmat);
  // iteration-independent GRU-input precomputes (NO atomics):
  prew_gemm<<<72, 256, 0, stream>>>(csum, 512, 512, 0,   Wih, cw);    // cw  = csum @ Wih[:,:512]^T
  prew_gemm<<<72, 256, 0, stream>>>(knw,  112, 112, 512, Wih, gknw);  // gknw = knw @ Wih[:,512:]^T

  for (int it = 0; it < 3; ++it) {
    float* attn = out + SLOT + (size_t)it * SLOT;
    lnqsum_kernel<<<Bc, 64, 0, stream>>>(cur, Wq, lsg, lsb, qsum);
    dots_kernel<<<BLn, 64, 0, stream>>>(kmat, qsum, attn);
    gxmix_kernel<<<Bc, 128, 0, stream>>>(attn, cw, gknw, gx);
    gate_kernel<<<BLn, 64, 0, stream>>>(cur, gx, Whh, bih, bhh, lfg, lfb, b2, ffb, nxt);
    mlp1_kernel<<<72 * 4, 256, 0, stream>>>(ffb, W1, b1, mid);
    mlp2_kernel<<<72, 256, 0, stream>>>(mid, W2, nxt);
    float* tmp = cur; cur = nxt; nxt = tmp;
  }
  copy_kernel<<<SLOT / 256, 256, 0, stream>>>(cur, out);
}